// Round 16
// baseline (96.592 us; speedup 1.0000x reference)
//
#include <hip/hip_runtime.h>
#include <math.h>

#define NBLK 784
#define O_ 32
#define N_ 144
#define PS 20    // padded LDS row stride for P (floats)
#define RS 148   // padded LDS row stride for R (floats)
#define LOG2PI_16 29.406033062549525f   // 16*log(2*pi)

// DPP-based 8-lane allreduce (groups s = t&7 are DPP-row aligned)
#define DPPADD(x, ctrl) ((x) + __int_as_float(                                 \
    __builtin_amdgcn_update_dpp(0, __float_as_int(x), ctrl, 0xF, 0xF, true)))
__device__ __forceinline__ float sum8(float x) {
    x = DPPADD(x, 0xB1);    // quad_perm 1,0,3,2
    x = DPPADD(x, 0x4E);    // quad_perm 2,3,0,1
    x = DPPADD(x, 0x141);   // row_half_mirror
    return x;
}

#define KLOAD(dst, nn) do {                                                    \
    const float4* Kp_ = (const float4*)(Kbase + (nn) * 16);                    \
    ((float4*)(dst))[0] = Kp_[0]; ((float4*)(dst))[1] = Kp_[1];                \
    ((float4*)(dst))[2] = Kp_[2]; ((float4*)(dst))[3] = Kp_[3];                \
} while (0)

// shared vote+moment accumulation body (r_ already computed)
#define MOMBODY(nn, kv) do {                                                   \
    rs += r_;                                                                  \
    float pv[16];                                                              \
    const float4* Pp_ = (const float4*)(P + (nn) * PS);                        \
    ((float4*)pv)[0] = Pp_[0]; ((float4*)pv)[1] = Pp_[1];                      \
    ((float4*)pv)[2] = Pp_[2]; ((float4*)pv)[3] = Pp_[3];                      \
    _Pragma("unroll")                                                          \
    for (int i_ = 0; i_ < 4; ++i_) {                                           \
        _Pragma("unroll")                                                      \
        for (int l_ = 0; l_ < 4; ++l_) {                                       \
            float v_ = fmaf(pv[i_*4+0], (kv)[0+l_],                            \
                       fmaf(pv[i_*4+1], (kv)[4+l_],                            \
                       fmaf(pv[i_*4+2], (kv)[8+l_],                            \
                            pv[i_*4+3] * (kv)[12+l_])));                       \
            S1[i_*4+l_] = fmaf(r_, v_, S1[i_*4+l_]);                           \
            S2[i_*4+l_] = fmaf(r_ * v_, v_, S2[i_*4+l_]);                      \
        }                                                                      \
    }                                                                          \
} while (0)

// pass-2 step: votes + Q + logit write
#define STEP2(nn, kv) do {                                                     \
    float pv[16];                                                              \
    const float4* Pp_ = (const float4*)(P + (nn) * PS);                        \
    ((float4*)pv)[0] = Pp_[0]; ((float4*)pv)[1] = Pp_[1];                      \
    ((float4*)pv)[2] = Pp_[2]; ((float4*)pv)[3] = Pp_[3];                      \
    float Q_ = 0.f;                                                            \
    _Pragma("unroll")                                                          \
    for (int i_ = 0; i_ < 4; ++i_) {                                           \
        _Pragma("unroll")                                                      \
        for (int l_ = 0; l_ < 4; ++l_) {                                       \
            float v_ = fmaf(pv[i_*4+0], (kv)[0+l_],                            \
                       fmaf(pv[i_*4+1], (kv)[4+l_],                            \
                       fmaf(pv[i_*4+2], (kv)[8+l_],                            \
                            pv[i_*4+3] * (kv)[12+l_])));                       \
            Q_ = fmaf(fmaf(isg[i_*4+l_], v_, qb[i_*4+l_]), v_, Q_);            \
        }                                                                      \
    }                                                                          \
    Rm[o * RS + (nn)] = fmaf(-0.5f, Q_, LC);                                   \
} while (0)

__global__ __launch_bounds__(256) void convcaps_em(
    const float* __restrict__ poses,
    const float* __restrict__ acts,
    const float* __restrict__ kern,
    const float* __restrict__ beta_a,
    const float* __restrict__ beta_u,
    float* __restrict__ out)
{
    const int pix = blockIdx.x;          // b*196 + ho*14 + wo
    const int b  = pix / 196;
    const int hw = pix - b * 196;
    const int ho = hw / 14;
    const int wo = hw - ho * 14;

    __shared__ __align__(16) float P[N_ * PS];   // pose blocks [n][d]
    __shared__ float A[N_];                      // a_in
    __shared__ float Rm[O_ * RS];                // logits [o][n]
    __shared__ float Mx[N_];                     // per-n logit max
    __shared__ float Sc[N_];                     // per-n A/sum_exp

    const int t = threadIdx.x;

    // ---- stage pose block + activations
    for (int idx = t; idx < N_ * 16; idx += 256) {
        int n = idx >> 4, d = idx & 15;
        int ki = n / 48, kj = (n >> 4) - ki * 3, c = n & 15;
        P[n * PS + d] = poses[((b * 16 + ho + ki) * 16 + (wo + kj)) * 256 + c * 16 + d];
    }
    if (t < N_) {
        int n = t;
        int ki = n / 48, kj = (n >> 4) - ki * 3, c = n & 15;
        A[n] = acts[((b * 16 + ho + ki) * 16 + (wo + kj)) * 16 + c];
    }
    __syncthreads();

    const int o = t >> 3;                        // 32 capsules
    const int s = t & 7;                         // 8 lanes per capsule, n-slice
    const float buv = beta_u[o];
    const float ba  = beta_a[o];
    const float* Kbase = kern + (size_t)o * (N_ * 16);

    float a_out = 0.f;
    float mu[16], sig[16];
    float kA[16], kB[16];
    float S1[16], S2[16], rs, L;

    // ===== iter 0, pass 1: r = A[n]/32 (A prefetched dist 1) =====
#pragma unroll
    for (int d = 0; d < 16; ++d) { S1[d] = 0.f; S2[d] = 0.f; }
    rs = 0.f;
    KLOAD(kA, s);
    float aA = A[s], aB;
#pragma unroll 1
    for (int k2 = 0; k2 < 9; ++k2) {
        const int nA = s + (k2 << 4);
        KLOAD(kB, nA + 8);
        aB = A[nA + 8];
        { const float r_ = aA * 0.03125f; MOMBODY(nA, kA); }
        if (k2 < 8) { KLOAD(kA, nA + 16); aA = A[nA + 16]; }
        { const float r_ = aB * 0.03125f; MOMBODY(nA + 8, kB); }
    }
    rs = sum8(rs);
#pragma unroll
    for (int d = 0; d < 16; ++d) { S1[d] = sum8(S1[d]); S2[d] = sum8(S2[d]); }
    {
        rs += 1e-9f;
        const float inv_rs = 1.0f / rs;
#pragma unroll
        for (int d = 0; d < 16; ++d) {
            mu[d] = S1[d] * inv_rs;
            sig[d] = fmaf(-mu[d], mu[d], S2[d] * inv_rs) + 1e-9f;
        }
        L = __logf(sig[0]  * sig[1])  + __logf(sig[2]  * sig[3])
          + __logf(sig[4]  * sig[5])  + __logf(sig[6]  * sig[7])
          + __logf(sig[8]  * sig[9])  + __logf(sig[10] * sig[11])
          + __logf(sig[12] * sig[13]) + __logf(sig[14] * sig[15]);
        const float cost = rs * fmaf(0.5f, L, 16.0f * buv);
        a_out = 1.0f / (1.0f + __expf(-(ba - cost)));
    }

    // ===== iters 1,2 =====
#pragma unroll 1
    for (int it = 1; it < 3; ++it) {
        // prep logit constants from previous stats
        float isg[16], qb[16];
        float c0 = 0.f;
#pragma unroll
        for (int d = 0; d < 16; ++d) {
            isg[d] = 1.0f / sig[d];
            qb[d]  = -2.0f * mu[d] * isg[d];
            c0     = fmaf(mu[d] * mu[d], isg[d], c0);
        }
        const float LC = __logf(a_out + 1e-9f)
                       - 0.5f * (LOG2PI_16 + L) - 0.5f * c0;

        // pass 2: logits into Rm (same-thread slots; no barrier needed before)
        KLOAD(kA, s);
#pragma unroll 1
        for (int k2 = 0; k2 < 9; ++k2) {
            const int nA = s + (k2 << 4);
            KLOAD(kB, nA + 8);
            STEP2(nA, kA);
            if (k2 < 8) KLOAD(kA, nA + 16);
            STEP2(nA + 8, kB);
        }
        __syncthreads();

        // softmax-lite: per n, tree max + tree sum; write only Mx, Sc
        if (t < N_) {
            float v[32];
#pragma unroll
            for (int oo = 0; oo < 32; ++oo) v[oo] = Rm[oo * RS + t];
            float m[16];
#pragma unroll
            for (int i = 0; i < 16; ++i) m[i] = fmaxf(v[i], v[i + 16]);
#pragma unroll
            for (int i = 0; i < 8; ++i)  m[i] = fmaxf(m[i], m[i + 8]);
#pragma unroll
            for (int i = 0; i < 4; ++i)  m[i] = fmaxf(m[i], m[i + 4]);
            const float mx = fmaxf(fmaxf(m[0], m[1]), fmaxf(m[2], m[3]));
#pragma unroll
            for (int oo = 0; oo < 32; ++oo) v[oo] = __expf(v[oo] - mx);
#pragma unroll
            for (int i = 0; i < 16; ++i) v[i] += v[i + 16];
#pragma unroll
            for (int i = 0; i < 8; ++i)  v[i] += v[i + 8];
#pragma unroll
            for (int i = 0; i < 4; ++i)  v[i] += v[i + 4];
            const float sm = (v[0] + v[1]) + (v[2] + v[3]);
            Mx[t] = mx;
            Sc[t] = A[t] / sm;
        }
        __syncthreads();

        // pass 1: r = exp(logit - Mx)·Sc, all scalar LDS inputs prefetched dist 1
#pragma unroll
        for (int d = 0; d < 16; ++d) { S1[d] = 0.f; S2[d] = 0.f; }
        rs = 0.f;
        KLOAD(kA, s);
        float lgA = Rm[o * RS + s], mxA = Mx[s], scA = Sc[s];
        float lgB, mxB, scB;
#pragma unroll 1
        for (int k2 = 0; k2 < 9; ++k2) {
            const int nA = s + (k2 << 4);
            KLOAD(kB, nA + 8);
            lgB = Rm[o * RS + nA + 8]; mxB = Mx[nA + 8]; scB = Sc[nA + 8];
            { const float r_ = __expf(lgA - mxA) * scA; MOMBODY(nA, kA); }
            if (k2 < 8) {
                KLOAD(kA, nA + 16);
                lgA = Rm[o * RS + nA + 16]; mxA = Mx[nA + 16]; scA = Sc[nA + 16];
            }
            { const float r_ = __expf(lgB - mxB) * scB; MOMBODY(nA + 8, kB); }
        }
        rs = sum8(rs);
#pragma unroll
        for (int d = 0; d < 16; ++d) { S1[d] = sum8(S1[d]); S2[d] = sum8(S2[d]); }

        rs += 1e-9f;
        const float inv_rs = 1.0f / rs;
#pragma unroll
        for (int d = 0; d < 16; ++d) {
            mu[d] = S1[d] * inv_rs;
            sig[d] = fmaf(-mu[d], mu[d], S2[d] * inv_rs) + 1e-9f;
        }
        L = __logf(sig[0]  * sig[1])  + __logf(sig[2]  * sig[3])
          + __logf(sig[4]  * sig[5])  + __logf(sig[6]  * sig[7])
          + __logf(sig[8]  * sig[9])  + __logf(sig[10] * sig[11])
          + __logf(sig[12] * sig[13]) + __logf(sig[14] * sig[15]);
        const float cost = rs * fmaf(0.5f, L, 16.0f * buv);
        const float x = (float)(it + 1) * (ba - cost);
        a_out = 1.0f / (1.0f + __expf(-x));
    }

    // ===== outputs: poses [pix][o][16] then a_out [pix][o] =====
    if (s == 0) {
        float4* ob = (float4*)(out + (size_t)pix * 512 + o * 16);
        ob[0] = make_float4(mu[0],  mu[1],  mu[2],  mu[3]);
        ob[1] = make_float4(mu[4],  mu[5],  mu[6],  mu[7]);
        ob[2] = make_float4(mu[8],  mu[9],  mu[10], mu[11]);
        ob[3] = make_float4(mu[12], mu[13], mu[14], mu[15]);
        out[401408 + pix * 32 + o] = a_out;
    }
}

extern "C" void kernel_launch(void* const* d_in, const int* in_sizes, int n_in,
                              void* d_out, int out_size, void* d_ws, size_t ws_size,
                              hipStream_t stream)
{
    const float* poses  = (const float*)d_in[0];
    const float* acts   = (const float*)d_in[1];
    const float* kern   = (const float*)d_in[2];
    const float* beta_a = (const float*)d_in[3];
    const float* beta_u = (const float*)d_in[4];
    float* out = (float*)d_out;
    convcaps_em<<<NBLK, 256, 0, stream>>>(poses, acts, kern, beta_a, beta_u, out);
}

// Round 17
// 95.108 us; speedup vs baseline: 1.0156x; 1.0156x over previous
//
#include <hip/hip_runtime.h>
#include <math.h>

#define NBLK 784
#define O_ 32
#define N_ 144
#define PS 20    // padded LDS row stride for P (floats)
#define RS 148   // padded LDS row stride for R (floats)
#define LOG2PI_16 29.406033062549525f   // 16*log(2*pi)

// DPP-based 8-lane allreduce (groups s = t&7 are DPP-row aligned)
#define DPPADD(x, ctrl) ((x) + __int_as_float(                                 \
    __builtin_amdgcn_update_dpp(0, __float_as_int(x), ctrl, 0xF, 0xF, true)))
__device__ __forceinline__ float sum8(float x) {
    x = DPPADD(x, 0xB1);    // quad_perm 1,0,3,2
    x = DPPADD(x, 0x4E);    // quad_perm 2,3,0,1
    x = DPPADD(x, 0x141);   // row_half_mirror
    return x;
}

#define KLOAD(dst, nn) do {                                                    \
    const float4* Kp_ = (const float4*)(Kbase + (nn) * 16);                    \
    ((float4*)(dst))[0] = Kp_[0]; ((float4*)(dst))[1] = Kp_[1];                \
    ((float4*)(dst))[2] = Kp_[2]; ((float4*)(dst))[3] = Kp_[3];                \
} while (0)

// shared vote+moment accumulation body (r_ already computed)
#define MOMBODY(nn, kv) do {                                                   \
    rs += r_;                                                                  \
    float pv[16];                                                              \
    const float4* Pp_ = (const float4*)(P + (nn) * PS);                        \
    ((float4*)pv)[0] = Pp_[0]; ((float4*)pv)[1] = Pp_[1];                      \
    ((float4*)pv)[2] = Pp_[2]; ((float4*)pv)[3] = Pp_[3];                      \
    _Pragma("unroll")                                                          \
    for (int i_ = 0; i_ < 4; ++i_) {                                           \
        _Pragma("unroll")                                                      \
        for (int l_ = 0; l_ < 4; ++l_) {                                       \
            float v_ = fmaf(pv[i_*4+0], (kv)[0+l_],                            \
                       fmaf(pv[i_*4+1], (kv)[4+l_],                            \
                       fmaf(pv[i_*4+2], (kv)[8+l_],                            \
                            pv[i_*4+3] * (kv)[12+l_])));                       \
            S1[i_*4+l_] = fmaf(r_, v_, S1[i_*4+l_]);                           \
            S2[i_*4+l_] = fmaf(r_ * v_, v_, S2[i_*4+l_]);                      \
        }                                                                      \
    }                                                                          \
} while (0)

// iter-0 pass-1 step: r = A[n]/32
#define STEP1_0(nn, kv) do {                                                   \
    const float r_ = A[(nn)] * 0.03125f;                                       \
    MOMBODY(nn, kv);                                                           \
} while (0)

// iter>=1 pass-1 step: r = exp(logit - Mx)·Sc (deferred softmax)
#define STEP1E(nn, kv) do {                                                    \
    const float r_ = __expf(Rm[o * RS + (nn)] - Mx[(nn)]) * Sc[(nn)];          \
    MOMBODY(nn, kv);                                                           \
} while (0)

// pass-2 step: votes + Q + logit write
#define STEP2(nn, kv) do {                                                     \
    float pv[16];                                                              \
    const float4* Pp_ = (const float4*)(P + (nn) * PS);                        \
    ((float4*)pv)[0] = Pp_[0]; ((float4*)pv)[1] = Pp_[1];                      \
    ((float4*)pv)[2] = Pp_[2]; ((float4*)pv)[3] = Pp_[3];                      \
    float Q_ = 0.f;                                                            \
    _Pragma("unroll")                                                          \
    for (int i_ = 0; i_ < 4; ++i_) {                                           \
        _Pragma("unroll")                                                      \
        for (int l_ = 0; l_ < 4; ++l_) {                                       \
            float v_ = fmaf(pv[i_*4+0], (kv)[0+l_],                            \
                       fmaf(pv[i_*4+1], (kv)[4+l_],                            \
                       fmaf(pv[i_*4+2], (kv)[8+l_],                            \
                            pv[i_*4+3] * (kv)[12+l_])));                       \
            Q_ = fmaf(fmaf(isg[i_*4+l_], v_, qb[i_*4+l_]), v_, Q_);            \
        }                                                                      \
    }                                                                          \
    Rm[o * RS + (nn)] = fmaf(-0.5f, Q_, LC);                                   \
} while (0)

// 3-buffer dist-2 K-prefetch sweep: STEP applied to n = s + 8k, k = 0..17.
// Entering iter k3: kA = K(3k3), kB = K(3k3+1). Guarded tail loads (o=31 OOB).
#define SWEEP(STEP) do {                                                       \
    KLOAD(kA, s); KLOAD(kB, s + 8);                                            \
    _Pragma("unroll 1")                                                        \
    for (int k3 = 0; k3 < 6; ++k3) {                                           \
        const int nb = s + k3 * 24;                                            \
        KLOAD(kC, nb + 16);                                                    \
        STEP(nb, kA);                                                          \
        if (k3 < 5) KLOAD(kA, nb + 24);                                        \
        STEP(nb + 8, kB);                                                      \
        if (k3 < 5) KLOAD(kB, nb + 32);                                        \
        STEP(nb + 16, kC);                                                     \
    }                                                                          \
} while (0)

__global__ __launch_bounds__(256) void convcaps_em(
    const float* __restrict__ poses,
    const float* __restrict__ acts,
    const float* __restrict__ kern,
    const float* __restrict__ beta_a,
    const float* __restrict__ beta_u,
    float* __restrict__ out)
{
    const int pix = blockIdx.x;          // b*196 + ho*14 + wo
    const int b  = pix / 196;
    const int hw = pix - b * 196;
    const int ho = hw / 14;
    const int wo = hw - ho * 14;

    __shared__ __align__(16) float P[N_ * PS];   // pose blocks [n][d]
    __shared__ float A[N_];                      // a_in
    __shared__ float Rm[O_ * RS];                // logits [o][n]
    __shared__ float Mx[N_];                     // per-n logit max
    __shared__ float Sc[N_];                     // per-n A/sum_exp

    const int t = threadIdx.x;

    // ---- stage pose block + activations
    for (int idx = t; idx < N_ * 16; idx += 256) {
        int n = idx >> 4, d = idx & 15;
        int ki = n / 48, kj = (n >> 4) - ki * 3, c = n & 15;
        P[n * PS + d] = poses[((b * 16 + ho + ki) * 16 + (wo + kj)) * 256 + c * 16 + d];
    }
    if (t < N_) {
        int n = t;
        int ki = n / 48, kj = (n >> 4) - ki * 3, c = n & 15;
        A[n] = acts[((b * 16 + ho + ki) * 16 + (wo + kj)) * 16 + c];
    }
    __syncthreads();

    const int o = t >> 3;                        // 32 capsules
    const int s = t & 7;                         // 8 lanes per capsule, n-slice
    const float buv = beta_u[o];
    const float ba  = beta_a[o];
    const float* Kbase = kern + (size_t)o * (N_ * 16);

    float a_out = 0.f;
    float mu[16], sig[16];
    float kA[16], kB[16], kC[16];
    float S1[16], S2[16], rs, L;

    // ===== iter 0, pass 1: r = A[n]/32 =====
#pragma unroll
    for (int d = 0; d < 16; ++d) { S1[d] = 0.f; S2[d] = 0.f; }
    rs = 0.f;
    SWEEP(STEP1_0);
    rs = sum8(rs);
#pragma unroll
    for (int d = 0; d < 16; ++d) { S1[d] = sum8(S1[d]); S2[d] = sum8(S2[d]); }
    {
        rs += 1e-9f;
        const float inv_rs = 1.0f / rs;
#pragma unroll
        for (int d = 0; d < 16; ++d) {
            mu[d] = S1[d] * inv_rs;
            sig[d] = fmaf(-mu[d], mu[d], S2[d] * inv_rs) + 1e-9f;
        }
        L = __logf(sig[0]  * sig[1])  + __logf(sig[2]  * sig[3])
          + __logf(sig[4]  * sig[5])  + __logf(sig[6]  * sig[7])
          + __logf(sig[8]  * sig[9])  + __logf(sig[10] * sig[11])
          + __logf(sig[12] * sig[13]) + __logf(sig[14] * sig[15]);
        const float cost = rs * fmaf(0.5f, L, 16.0f * buv);
        a_out = 1.0f / (1.0f + __expf(-(ba - cost)));
    }

    // ===== iters 1,2 =====
#pragma unroll 1
    for (int it = 1; it < 3; ++it) {
        // prep logit constants from previous stats
        float isg[16], qb[16];
        float c0 = 0.f;
#pragma unroll
        for (int d = 0; d < 16; ++d) {
            isg[d] = 1.0f / sig[d];
            qb[d]  = -2.0f * mu[d] * isg[d];
            c0     = fmaf(mu[d] * mu[d], isg[d], c0);
        }
        const float LC = __logf(a_out + 1e-9f)
                       - 0.5f * (LOG2PI_16 + L) - 0.5f * c0;

        // pass 2: logits into Rm (same-thread slots; no barrier needed before)
        SWEEP(STEP2);
        __syncthreads();

        // softmax-lite: per n, tree max + tree sum; write only Mx, Sc
        if (t < N_) {
            float v[32];
#pragma unroll
            for (int oo = 0; oo < 32; ++oo) v[oo] = Rm[oo * RS + t];
            float m[16];
#pragma unroll
            for (int i = 0; i < 16; ++i) m[i] = fmaxf(v[i], v[i + 16]);
#pragma unroll
            for (int i = 0; i < 8; ++i)  m[i] = fmaxf(m[i], m[i + 8]);
#pragma unroll
            for (int i = 0; i < 4; ++i)  m[i] = fmaxf(m[i], m[i + 4]);
            const float mx = fmaxf(fmaxf(m[0], m[1]), fmaxf(m[2], m[3]));
#pragma unroll
            for (int oo = 0; oo < 32; ++oo) v[oo] = __expf(v[oo] - mx);
#pragma unroll
            for (int i = 0; i < 16; ++i) v[i] += v[i + 16];
#pragma unroll
            for (int i = 0; i < 8; ++i)  v[i] += v[i + 8];
#pragma unroll
            for (int i = 0; i < 4; ++i)  v[i] += v[i + 4];
            const float sm = (v[0] + v[1]) + (v[2] + v[3]);
            Mx[t] = mx;
            Sc[t] = A[t] / sm;
        }
        __syncthreads();

        // pass 1: r = exp(logit - Mx)·Sc
#pragma unroll
        for (int d = 0; d < 16; ++d) { S1[d] = 0.f; S2[d] = 0.f; }
        rs = 0.f;
        SWEEP(STEP1E);
        rs = sum8(rs);
#pragma unroll
        for (int d = 0; d < 16; ++d) { S1[d] = sum8(S1[d]); S2[d] = sum8(S2[d]); }

        rs += 1e-9f;
        const float inv_rs = 1.0f / rs;
#pragma unroll
        for (int d = 0; d < 16; ++d) {
            mu[d] = S1[d] * inv_rs;
            sig[d] = fmaf(-mu[d], mu[d], S2[d] * inv_rs) + 1e-9f;
        }
        L = __logf(sig[0]  * sig[1])  + __logf(sig[2]  * sig[3])
          + __logf(sig[4]  * sig[5])  + __logf(sig[6]  * sig[7])
          + __logf(sig[8]  * sig[9])  + __logf(sig[10] * sig[11])
          + __logf(sig[12] * sig[13]) + __logf(sig[14] * sig[15]);
        const float cost = rs * fmaf(0.5f, L, 16.0f * buv);
        const float x = (float)(it + 1) * (ba - cost);
        a_out = 1.0f / (1.0f + __expf(-x));
    }

    // ===== outputs: poses [pix][o][16] then a_out [pix][o] =====
    if (s == 0) {
        float4* ob = (float4*)(out + (size_t)pix * 512 + o * 16);
        ob[0] = make_float4(mu[0],  mu[1],  mu[2],  mu[3]);
        ob[1] = make_float4(mu[4],  mu[5],  mu[6],  mu[7]);
        ob[2] = make_float4(mu[8],  mu[9],  mu[10], mu[11]);
        ob[3] = make_float4(mu[12], mu[13], mu[14], mu[15]);
        out[401408 + pix * 32 + o] = a_out;
    }
}

extern "C" void kernel_launch(void* const* d_in, const int* in_sizes, int n_in,
                              void* d_out, int out_size, void* d_ws, size_t ws_size,
                              hipStream_t stream)
{
    const float* poses  = (const float*)d_in[0];
    const float* acts   = (const float*)d_in[1];
    const float* kern   = (const float*)d_in[2];
    const float* beta_a = (const float*)d_in[3];
    const float* beta_u = (const float*)d_in[4];
    float* out = (float*)d_out;
    convcaps_em<<<NBLK, 256, 0, stream>>>(poses, acts, kern, beta_a, beta_u, out);
}